// Round 12
// baseline (419.074 us; speedup 1.0000x reference)
//
#include <hip/hip_runtime.h>
#include <stdint.h>

typedef unsigned short u16;
typedef __attribute__((ext_vector_type(8))) short short8;
typedef __attribute__((ext_vector_type(4))) float floatx4;

#define MFMA16(a, b, c) __builtin_amdgcn_mfma_f32_16x16x32_bf16(a, b, c, 0, 0, 0)

static __device__ __forceinline__ void gl_lds16(const void* g, void* l) {
  __builtin_amdgcn_global_load_lds(
      (const __attribute__((address_space(1))) uint32_t*)g,
      (__attribute__((address_space(3))) uint32_t*)l, 16, 0, 0);
}

static __device__ __forceinline__ float b2f(u16 u) {
  union { float f; unsigned u; } v;
  v.u = ((unsigned)u) << 16;
  return v.f;
}
static __device__ __forceinline__ u16 f2b(float f) {
  union { float f; unsigned u; } v;
  v.f = f;
  unsigned r = v.u + 0x7fffu + ((v.u >> 16) & 1u);  // RNE
  return (u16)(r >> 16);
}
// Cheap round-half-up bf16 (2 VALU ops). P-store only (values in [0,1]).
static __device__ __forceinline__ u16 f2b_rn(float f) {
  union { float f; unsigned u; } v;
  v.f = f;
  return (u16)((v.u + 0x8000u) >> 16);
}

// flag[0..31]: per-block large-exponent counts (plain stores from detect;
// idempotent across graph replays — no memset node needed).
static __device__ __forceinline__ int is_f32(const int* __restrict__ flag) {
  int s = 0;
#pragma unroll
  for (int i = 0; i < 32; ++i) s += flag[i];
  return s > 1000;
}

// DPP row-rotate reductions over 16-lane groups (VALU, no LDS traffic).
template <int CTRL>
static __device__ __forceinline__ float dppf(float x) {
  return __builtin_bit_cast(
      float, __builtin_amdgcn_update_dpp(0, __builtin_bit_cast(int, x), CTRL,
                                         0xF, 0xF, true));
}
static __device__ __forceinline__ float sum16(float x) {
  x += dppf<0x128>(x);
  x += dppf<0x124>(x);
  x += dppf<0x122>(x);
  x += dppf<0x121>(x);
  return x;
}
static __device__ __forceinline__ float max16(float x) {
  x = fmaxf(x, dppf<0x128>(x));
  x = fmaxf(x, dppf<0x124>(x));
  x = fmaxf(x, dppf<0x122>(x));
  x = fmaxf(x, dppf<0x121>(x));
  return x;
}

// ---------------------------------------------------------------------------
// Input-dtype detector (parallel, proven; per-block plain stores).
// ---------------------------------------------------------------------------
__global__ __launch_bounds__(256) void detect_f32(const u16* __restrict__ x,
                                                  int* __restrict__ flag) {
  __shared__ int cnt[256];
  int i = blockIdx.x * 256 + threadIdx.x;  // 8192 threads x 8 u16 = 64K u16
  short8 v = ((const short8*)x)[i];
  int c = 0;
#pragma unroll
  for (int j = 0; j < 8; ++j) {
    int e = (((unsigned short)v[j]) >> 7) & 0xFF;
    c += (e >= 140) ? 1 : 0;
  }
  cnt[threadIdx.x] = c;
  __syncthreads();
  for (int s = 128; s > 0; s >>= 1) {
    if (threadIdx.x < (unsigned)s) cnt[threadIdx.x] += cnt[threadIdx.x + s];
    __syncthreads();
  }
  if (threadIdx.x == 0) flag[blockIdx.x] = cnt[0];
}

static __device__ __forceinline__ void conv8_body(const void* __restrict__ src,
                                                  u16* __restrict__ dst, int i,
                                                  int f32) {
  short8 r;
  if (f32) {
    const float4* s = (const float4*)src;
    float4 a = s[2 * i], b = s[2 * i + 1];
    r[0] = (short)f2b(a.x); r[1] = (short)f2b(a.y);
    r[2] = (short)f2b(a.z); r[3] = (short)f2b(a.w);
    r[4] = (short)f2b(b.x); r[5] = (short)f2b(b.y);
    r[6] = (short)f2b(b.z); r[7] = (short)f2b(b.w);
  } else {
    r = ((const short8*)src)[i];
  }
  ((short8*)dst)[i] = r;
}

// Standalone convert (wo, post-flash).
__global__ __launch_bounds__(256) void convert_in8(const void* __restrict__ src,
                                                   u16* __restrict__ dst, int n8,
                                                   const int* __restrict__ flag) {
  int i = blockIdx.x * 256 + threadIdx.x;
  if (i >= n8) return;
  conv8_body(src, dst, i, is_f32(flag));
}

// ---------------------------------------------------------------------------
// prep_fused: convert x (bid<4096) + convert wq into d_out scratch
// (bid<6144; d_out is dead until the final O GEMM overwrites it fully) +
// transpose wkv -> Wbuf (bid<14336). Whole blocks per branch.
// ---------------------------------------------------------------------------
__global__ __launch_bounds__(256) void prep_fused(const void* __restrict__ x,
                                                  const void* __restrict__ wq,
                                                  const void* __restrict__ wkv,
                                                  u16* __restrict__ xb,
                                                  u16* __restrict__ wqd,
                                                  u16* __restrict__ wkvT,
                                                  const int* __restrict__ flag) {
  __shared__ u16 tile[32][33];
  int bid = blockIdx.x;
  int f = is_f32(flag);
  if (bid < 4096) {
    conv8_body(x, xb, bid * 256 + threadIdx.x, f);
  } else if (bid < 6144) {
    conv8_body(wq, wqd, (bid - 4096) * 256 + threadIdx.x, f);
  } else {
    int tb = bid - 6144;  // 0..8191: wkv [2048][4096] -> wkvT [4096][2048]
    int c0 = (tb & 127) * 32, r0 = (tb >> 7) * 32;
    int lx = threadIdx.x & 31, ly = threadIdx.x >> 5;
#pragma unroll
    for (int i = 0; i < 32; i += 8) {
      size_t idx = (size_t)(r0 + ly + i) * 4096 + c0 + lx;
      tile[ly + i][lx] = f ? f2b(((const float*)wkv)[idx]) : ((const u16*)wkv)[idx];
    }
    __syncthreads();
#pragma unroll
    for (int i = 0; i < 32; i += 8)
      wkvT[(size_t)(c0 + ly + i) * 2048 + r0 + lx] = tile[lx][ly + i];
  }
}

// ---------------------------------------------------------------------------
// mid_fused: transpose_v (bid<8192; KVb V-cols -> Vt) + rope (bid>=8192;
// Qb + KVb K-cols in place). Regions disjoint — no sync needed.
// ---------------------------------------------------------------------------
__global__ __launch_bounds__(256) void mid_fused(u16* __restrict__ KV,
                                                 u16* __restrict__ Vt,
                                                 u16* __restrict__ Q) {
  __shared__ u16 tile[32][33];
  int bid = blockIdx.x;
  if (bid < 8192) {
    int b = bid >> 12;
    int d0 = (bid & 63) * 32, s0 = ((bid >> 6) & 63) * 32;
    int lx = threadIdx.x & 31, ly = threadIdx.x >> 5;
    const u16* src = KV + ((size_t)(b * 2048 + s0)) * 4096 + 2048 + d0;
#pragma unroll
    for (int i = 0; i < 32; i += 8)
      tile[ly + i][lx] = src[(size_t)(ly + i) * 4096 + lx];
    __syncthreads();
    u16* dst = Vt + ((size_t)(b * 2048 + d0)) * 2048 + s0;
#pragma unroll
    for (int i = 0; i < 32; i += 8)
      dst[(size_t)(ly + i) * 2048 + lx] = tile[lx][ly + i];
  } else {
    const float scale = 0.08838834764831845f;  // 1/sqrt(128)
    int idx = (bid - 8192) * 256 + threadIdx.x;
    int tok = idx >> 10;
    int rem = idx & 1023;
    int h = rem >> 6, i = rem & 63;
    int pos = tok & 2047;
    float f = __powf(10000.0f, -(float)(2 * i) * (1.0f / 128.0f));
    float ang = (float)pos * f;
    float s, c;
    sincosf(ang, &s, &c);

    size_t qb = (size_t)tok * 2048 + h * 128 + i;
    float q1 = b2f(Q[qb]), q2 = b2f(Q[qb + 64]);
    Q[qb] = f2b((q1 * c - q2 * s) * scale);
    Q[qb + 64] = f2b((q2 * c + q1 * s) * scale);

    size_t kb = (size_t)tok * 4096 + h * 128 + i;
    float k1 = b2f(KV[kb]), k2 = b2f(KV[kb + 64]);
    KV[kb] = f2b(k1 * c - k2 * s);
    KV[kb + 64] = f2b(k2 * c + k1 * s);
  }
}

// ---------------------------------------------------------------------------
// NT GEMM (m97 structure, proven) — O projection (512-block grid).
// ---------------------------------------------------------------------------
__global__ __launch_bounds__(256) void gemm_nt(const u16* __restrict__ A,
                                               const u16* __restrict__ Bm,
                                               void* __restrict__ Cv,
                                               int M, int N, int K,
                                               const int* __restrict__ flag,
                                               int flag_mode) {
  __shared__ u16 Ash[128 * 64];
  __shared__ u16 Bsh[128 * 64];
  int tid = threadIdx.x, w = tid >> 6, lane = tid & 63;
  int quad = lane >> 4, l15 = lane & 15;
  int m0 = blockIdx.y * 128, n0 = blockIdx.x * 128;
  int wm = (w & 1) * 64, wn = (w >> 1) * 64;
  int f32out = flag_mode ? is_f32(flag) : 0;

  floatx4 acc[4][4];
#pragma unroll
  for (int i = 0; i < 4; ++i)
#pragma unroll
    for (int j = 0; j < 4; ++j) acc[i][j] = floatx4{0.f, 0.f, 0.f, 0.f};

  int srow = lane >> 3;
  int gch = (lane & 7) ^ srow;
  const u16* Ag = A + (size_t)(m0 + w * 32 + srow) * K + gch * 8;
  const u16* Bg = Bm + (size_t)(n0 + w * 32 + srow) * K + gch * 8;

  for (int k0 = 0; k0 < K; k0 += 64) {
    __syncthreads();
#pragma unroll
    for (int t = 0; t < 4; ++t) {
      gl_lds16(Ag + (size_t)t * 8 * K + k0, (void*)(Ash + (w * 32 + t * 8) * 64));
      gl_lds16(Bg + (size_t)t * 8 * K + k0, (void*)(Bsh + (w * 32 + t * 8) * 64));
    }
    __syncthreads();
#pragma unroll
    for (int kk = 0; kk < 2; ++kk) {
      int c = kk * 4 + quad;
      short8 af[4], bf[4];
#pragma unroll
      for (int i = 0; i < 4; ++i) {
        int m = wm + 16 * i + l15;
        af[i] = *(const short8*)(Ash + m * 64 + ((c ^ (m & 7)) << 3));
        int n = wn + 16 * i + l15;
        bf[i] = *(const short8*)(Bsh + n * 64 + ((c ^ (n & 7)) << 3));
      }
#pragma unroll
      for (int i = 0; i < 4; ++i)
#pragma unroll
        for (int j = 0; j < 4; ++j) acc[i][j] = MFMA16(af[i], bf[j], acc[i][j]);
    }
  }

#pragma unroll
  for (int i = 0; i < 4; ++i)
#pragma unroll
    for (int r = 0; r < 4; ++r) {
      int row = m0 + wm + 16 * i + quad * 4 + r;
      if (f32out) {
        float* cp = (float*)Cv + (size_t)row * N + n0 + wn + l15;
#pragma unroll
        for (int j = 0; j < 4; ++j) cp[16 * j] = acc[i][j][r];
      } else {
        u16* cp = (u16*)Cv + (size_t)row * N + n0 + wn + l15;
#pragma unroll
        for (int j = 0; j < 4; ++j) cp[16 * j] = f2b(acc[i][j][r]);
      }
    }
}

// ---------------------------------------------------------------------------
// gemm8qkv (round 12): merged Q + KV projection on the proven 8-phase 256^2
// gemm8 structure. N-space = 6144: cols [0,2048) -> B=wq (in d_out scratch),
// C=Qb ld 2048; cols [2048,6144) -> B=wkvT, C=KVb ld 4096. Per-block uniform
// branch; inner loop byte-identical to gemm8. Grid (24,16) = 384 blocks.
// ---------------------------------------------------------------------------
__global__ __launch_bounds__(512, 2) void gemm8qkv(const u16* __restrict__ A,
                                                   const u16* __restrict__ Bq,
                                                   const u16* __restrict__ Bkv,
                                                   u16* __restrict__ Cq,
                                                   u16* __restrict__ Ckv) {
  const int K = 2048;
  const int NT = K >> 6;
  __shared__ u16 Ash[2 * 256 * 64];
  __shared__ u16 Bsh[2 * 256 * 64];
  int tid = threadIdx.x, w = tid >> 6, lane = tid & 63;
  int quad = lane >> 4, l15 = lane & 15;
  int wr = w >> 2, wc = w & 3;
  int wm = wr * 128, wn = wc * 64;
  int m0 = blockIdx.y * 256;
  int n0g = blockIdx.x * 256;

  const u16* Bsrc;
  u16* Cd;
  int ldc, ncol;
  if (n0g < 2048) {
    Bsrc = Bq; Cd = Cq; ldc = 2048; ncol = n0g;
  } else {
    Bsrc = Bkv; Cd = Ckv; ldc = 4096; ncol = n0g - 2048;
  }

  int srow8 = lane >> 3;
  int gch = (lane & 7) ^ srow8;
  const u16* Ag = A + (size_t)(m0 + w * 8 + srow8) * K + gch * 8;
  const u16* Bg = Bsrc + (size_t)(ncol + w * 8 + srow8) * K + gch * 8;
  int ldsrow = w * 8;  // wave-uniform LDS row base; lane*16B added by HW

  floatx4 acc[8][4];
#pragma unroll
  for (int i = 0; i < 8; ++i)
#pragma unroll
    for (int j = 0; j < 4; ++j) acc[i][j] = floatx4{0.f, 0.f, 0.f, 0.f};

  int ch0 = ((quad ^ (l15 & 7)) << 3);        // kk=0 chunk byte-> u16 offset
  int ch1 = (((4 + quad) ^ (l15 & 7)) << 3);  // kk=1

  auto stage = [&](int qi) {
    int tau = qi >> 2;
    int tc = tau < NT ? tau : NT - 1;  // clamp keeps vmcnt counts exact
    int hh = qi & 3;                   // 0:B0 1:B1 2:A0 3:A1
    int half = (hh & 1) * 128;
    int sbuf = (tau & 1) * (256 * 64);
    size_t kof = (size_t)tc * 64;
    if (hh < 2) {
      gl_lds16(Bg + (size_t)half * K + kof,
               (void*)(Bsh + sbuf + (half + ldsrow) * 64));
      gl_lds16(Bg + (size_t)(half + 64) * K + kof,
               (void*)(Bsh + sbuf + (half + 64 + ldsrow) * 64));
    } else {
      gl_lds16(Ag + (size_t)half * K + kof,
               (void*)(Ash + sbuf + (half + ldsrow) * 64));
      gl_lds16(Ag + (size_t)(half + 64) * K + kof,
               (void*)(Ash + sbuf + (half + 64 + ldsrow) * 64));
    }
  };

  // Prologue: tile0 fully + 3 half-tiles of tile1 -> 3 half-tiles in flight.
  stage(0); stage(1); stage(2); stage(3);
  __asm__ volatile("s_waitcnt vmcnt(4)" ::: "memory");
  stage(4); stage(5); stage(6);
  __asm__ volatile("s_waitcnt vmcnt(6)" ::: "memory");
  __builtin_amdgcn_s_barrier();

  for (int t = 0; t < NT; ++t) {
    u16* As = Ash + (t & 1) * (256 * 64);
    u16* Bs = Bsh + (t & 1) * (256 * 64);
    if (t) {
      __asm__ volatile("s_waitcnt vmcnt(6)" ::: "memory");
      __builtin_amdgcn_s_barrier();
    }
    int qb = 7 + 4 * t;
    short8 bf[8], af0[8], af1[8];

    // ---- P0: read af0-kk0 + bf-kk0 (8 reads); MFMA mh0 x kk0 (16) ----
#pragma unroll
    for (int j = 0; j < 4; ++j) {
      int n = wn + 16 * j + l15;
      bf[2 * j] = *(const short8*)(Bs + n * 64 + ch0);
    }
#pragma unroll
    for (int i = 0; i < 4; ++i) {
      int m = wm + 16 * i + l15;
      af0[2 * i] = *(const short8*)(As + m * 64 + ch0);
    }
    stage(qb);
    __builtin_amdgcn_s_barrier();
    __asm__ volatile("s_waitcnt lgkmcnt(0)" ::: "memory");
    __builtin_amdgcn_sched_barrier(0);
    __builtin_amdgcn_s_setprio(1);
#pragma unroll
    for (int i = 0; i < 4; ++i)
#pragma unroll
      for (int j = 0; j < 4; ++j)
        acc[i][j] = MFMA16(af0[2 * i], bf[2 * j], acc[i][j]);
    __builtin_amdgcn_s_setprio(0);
    __builtin_amdgcn_s_barrier();

    // ---- P1: read af0-kk1 + bf-kk1 (8 reads); MFMA mh0 x kk1 (16) ----
#pragma unroll
    for (int j = 0; j < 4; ++j) {
      int n = wn + 16 * j + l15;
      bf[2 * j + 1] = *(const short8*)(Bs + n * 64 + ch1);
    }
#pragma unroll
    for (int i = 0; i < 4; ++i) {
      int m = wm + 16 * i + l15;
      af0[2 * i + 1] = *(const short8*)(As + m * 64 + ch1);
    }
    stage(qb + 1);
    __builtin_amdgcn_s_barrier();
    __asm__ volatile("s_waitcnt lgkmcnt(0)" ::: "memory");
    __builtin_amdgcn_sched_barrier(0);
    __builtin_amdgcn_s_setprio(1);
#pragma unroll
    for (int i = 0; i < 4; ++i)
#pragma unroll
      for (int j = 0; j < 4; ++j)
        acc[i][j] = MFMA16(af0[2 * i + 1], bf[2 * j + 1], acc[i][j]);
    __builtin_amdgcn_s_setprio(0);
    __builtin_amdgcn_s_barrier();

    // ---- P2: read af1-kk0 (4 reads); MFMA mh1 x kk0 (16) ----
#pragma unroll
    for (int i = 0; i < 4; ++i) {
      int m = wm + 64 + 16 * i + l15;
      af1[2 * i] = *(const short8*)(As + m * 64 + ch0);
    }
    stage(qb + 2);
    __builtin_amdgcn_s_barrier();
    __asm__ volatile("s_waitcnt lgkmcnt(0)" ::: "memory");
    __builtin_amdgcn_sched_barrier(0);
    __builtin_amdgcn_s_setprio(1);
#pragma unroll
    for (int i = 0; i < 4; ++i)
#pragma unroll
      for (int j = 0; j < 4; ++j)
        acc[4 + i][j] = MFMA16(af1[2 * i], bf[2 * j], acc[4 + i][j]);
    __builtin_amdgcn_s_setprio(0);
    __builtin_amdgcn_s_barrier();

    // ---- P3: read af1-kk1 (4 reads); MFMA mh1 x kk1 (16) ----
#pragma unroll
    for (int i = 0; i < 4; ++i) {
      int m = wm + 64 + 16 * i + l15;
      af1[2 * i + 1] = *(const short8*)(As + m * 64 + ch1);
    }
    stage(qb + 3);
    __builtin_amdgcn_s_barrier();
    __asm__ volatile("s_waitcnt lgkmcnt(0)" ::: "memory");
    __builtin_amdgcn_sched_barrier(0);
    __builtin_amdgcn_s_setprio(1);
#pragma unroll
    for (int i = 0; i < 4; ++i)
#pragma unroll
      for (int j = 0; j < 4; ++j)
        acc[4 + i][j] = MFMA16(af1[2 * i + 1], bf[2 * j + 1], acc[4 + i][j]);
    __builtin_amdgcn_s_setprio(0);
    __builtin_amdgcn_s_barrier();
  }

  // Epilogue: per-block destination (Qb or KVb), bf16 out.
#pragma unroll
  for (int i = 0; i < 8; ++i)
#pragma unroll
    for (int r = 0; r < 4; ++r) {
      int row = m0 + wm + 16 * i + quad * 4 + r;
      u16* cp = Cd + (size_t)row * ldc + ncol + wn + l15;
#pragma unroll
      for (int j = 0; j < 4; ++j) cp[16 * j] = f2b(acc[i][j][r]);
    }
}

// ---------------------------------------------------------------------------
// Flash attention v10 (proven round 10): KVBLK=128, K single-buffered, V
// dbuf, per-wave P; 512 blocks heavy-first. Unchanged.
// ---------------------------------------------------------------------------
__global__ __launch_bounds__(512, 1) void flash_attn(const u16* __restrict__ Q,
                                                     const u16* __restrict__ KV,
                                                     const u16* __restrict__ Vt,
                                                     u16* __restrict__ O) {
  const int S = 2048, D = 2048, KVld = 4096;
  int bh = blockIdx.x;            // 0..31
  int qt = 15 - (int)blockIdx.y;  // heavy-first dispatch
  int b = bh >> 4, h = bh & 15;
  int tid = threadIdx.x, w = tid >> 6, lane = tid & 63;
  int quad = lane >> 4, l15 = lane & 15;

  const u16* Qb = Q + (size_t)(b * S) * D + h * 128;
  const u16* Kb = KV + (size_t)(b * S) * KVld + h * 128;
  const u16* Vtb = Vt + ((size_t)(b * 2048 + h * 128)) * S;

  __shared__ u16 Ksh[128 * 128];     // single buf [krow][d], 16 chunks/row
  __shared__ u16 Vsh[2][128 * 128];  // dbuf [d][k], 16 chunks/row
  __shared__ u16 Psh[8][16 * 128];   // per-wave P [16 q][128 k]

  // K tile [128 rows][128 d]: wave w rows w*16..w*16+16, 4 instrs.
  auto stage_k = [&](int kt) {
    int kb = kt * 128;
#pragma unroll
    for (int tt = 0; tt < 4; ++tt) {
      int r0 = w * 16 + tt * 4;
      int row = r0 + quad;
      int g = (l15 & 8) | ((l15 & 7) ^ (row & 7));
      gl_lds16(Kb + (size_t)(kb + row) * KVld + g * 8, (void*)(Ksh + r0 * 128));
    }
  };
  // V^T tile [128 d][128 k]: wave w d-rows w*16..w*16+16, 4 instrs.
  auto stage_v = [&](int kt, int buf) {
    int kb = kt * 128;
#pragma unroll
    for (int tt = 0; tt < 4; ++tt) {
      int d0 = w * 16 + tt * 4;
      int d = d0 + quad;
      int g = (l15 & 8) | ((l15 & 7) ^ (d & 7));
      gl_lds16(Vtb + (size_t)d * S + kb + g * 8, (void*)(Vsh[buf] + d0 * 128));
    }
  };

  int qw = qt * 128 + w * 16;  // this wave's 16 q-rows

  short8 qf[4];
  {
    const u16* qp = Qb + (size_t)(qw + l15) * D + quad * 8;
#pragma unroll
    for (int kk = 0; kk < 4; ++kk) qf[kk] = *(const short8*)(qp + kk * 32);
  }

  floatx4 o[8];
#pragma unroll
  for (int t = 0; t < 8; ++t) o[t] = floatx4{0.f, 0.f, 0.f, 0.f};
  float mrow[4], lrow[4];
#pragma unroll
  for (int r = 0; r < 4; ++r) { mrow[r] = -1e30f; lrow[r] = 0.f; }

  int nk = qt + 1;  // 128-wide k-tiles
  stage_k(0);
  stage_v(0, 0);
  __syncthreads();

  for (int kt = 0; kt < nk; ++kt) {
    int kb = kt * 128;
    int cur = kt & 1;

    // --- QK^T: 8 nf x 4 kk = 32 MFMA (reads Ksh) ---
    floatx4 sc[8];
#pragma unroll
    for (int nf = 0; nf < 8; ++nf) sc[nf] = floatx4{0.f, 0.f, 0.f, 0.f};
#pragma unroll
    for (int kk = 0; kk < 4; ++kk) {
      int c = kk * 4 + quad;
#pragma unroll
      for (int nf = 0; nf < 8; ++nf) {
        int n = nf * 16 + l15;
        int pc = (c & 8) | ((c & 7) ^ (n & 7));
        short8 kf = *(const short8*)(Ksh + n * 128 + pc * 8);
        sc[nf] = MFMA16(qf[kk], kf, sc[nf]);
      }
    }
    // #1: all waves' K reads complete
    __syncthreads();
    // prefetch next tile: K into the (now unread) single buffer, V into buf^1
    if (kt + 1 < nk) {
      stage_k(kt + 1);
      stage_v(kt + 1, cur ^ 1);
    }

    // --- online softmax (1/sqrt(dh) pre-folded into Q) ---
    bool masked = (kb + 127 > qw);
    floatx4 alv;
#pragma unroll
    for (int r = 0; r < 4; ++r) {
      int qg = qw + quad * 4 + r;
      float p[8];
#pragma unroll
      for (int g = 0; g < 8; ++g) {
        float vg = sc[g][r];
        if (masked) vg = (kb + 16 * g + l15 <= qg) ? vg : -1e30f;
        p[g] = vg;
      }
      float mx = fmaxf(fmaxf(fmaxf(p[0], p[1]), fmaxf(p[2], p[3])),
                       fmaxf(fmaxf(p[4], p[5]), fmaxf(p[6], p[7])));
      mx = max16(mx);
      float mn = fmaxf(mrow[r], mx);
      float al = __expf(mrow[r] - mn);
      mrow[r] = mn;
      float rs = 0.f;
#pragma unroll
      for (int g = 0; g < 8; ++g) {
        p[g] = __expf(p[g] - mn);
        rs += p[g];
      }
      rs = sum16(rs);
      lrow[r] = lrow[r] * al + rs;
      alv[r] = al;
      int m_ = quad * 4 + r;
      int sw = (m_ & 3) ^ ((m_ >> 2) << 1);
      int cb = l15 >> 3, e = l15 & 7;
      u16* pr = Psh[w] + m_ * 128;
#pragma unroll
      for (int g = 0; g < 8; ++g)
        pr[(((2 * g + cb) ^ sw) << 3) + e] = f2b_rn(p[g]);
    }
    // defer-rescale: al==1.0 exactly when the running max didn't grow.
    if (__any((alv[0] != 1.f) || (alv[1] != 1.f) ||
              (alv[2] != 1.f) || (alv[3] != 1.f))) {
#pragma unroll
      for (int t = 0; t < 8; ++t) o[t] *= alv;
    }
    __asm__ volatile("s_waitcnt lgkmcnt(0)" ::: "memory");

    // --- PV: 8 d x 4 ksteps = 32 MFMA (reads Vsh[cur] + Psh[w]) ---
    int psw = (l15 & 3) ^ ((l15 >> 2) << 1);
#pragma unroll
    for (int ks = 0; ks < 4; ++ks) {
      int c = ks * 4 + quad;
      short8 pf = *(const short8*)(Psh[w] + l15 * 128 + ((c ^ psw) << 3));
#pragma unroll
      for (int t = 0; t < 8; ++t) {
        int d = t * 16 + l15;
        int pc = (c & 8) | ((c & 7) ^ (d & 7));
        short8 vf = *(const short8*)(Vsh[cur] + d * 128 + pc * 8);
        o[t] = MFMA16(pf, vf, o[t]);
      }
    }
    // #2: drains this wave's prefetch gl_lds + joins waves.
    __syncthreads();
  }

  // epilogue
#pragma unroll
  for (int r = 0; r < 4; ++r) {
    float inv = 1.0f / lrow[r];
    int qg = qw + quad * 4 + r;
    u16* op = O + (size_t)(b * S + qg) * D + h * 128;
#pragma unroll
    for (int t = 0; t < 8; ++t) op[t * 16 + l15] = f2b(o[t][r] * inv);
  }
}

// ---------------------------------------------------------------------------
// Launch (round 12: 7 nodes). ws (u16 after 64-elem flag pad):
//   xb 8.4M | Wbuf 8.4M (wkvT -> Vt -> wo) | Qb 8.4M | KVb 16.8M. ~84 MB.
//   wq staged in d_out (dead scratch; final O GEMM fully overwrites).
//   AO aliases xb.
// ---------------------------------------------------------------------------
extern "C" void kernel_launch(void* const* d_in, const int* in_sizes, int n_in,
                              void* d_out, int out_size, void* d_ws, size_t ws_size,
                              hipStream_t stream) {
  const void* x = d_in[0];
  const void* wq = d_in[1];
  const void* wkv = d_in[2];
  const void* wo = d_in[3];

  int* flag = (int*)d_ws;  // 32 ints (128 B = the 64-u16 pad)
  u16* xb = (u16*)d_ws + 64;
  u16* Wbuf = xb + (size_t)8388608;
  u16* Qb = Wbuf + (size_t)8388608;
  u16* KVb = Qb + (size_t)8388608;
  u16* wqd = (u16*)d_out;  // wq scratch in d_out (dead until final GEMM)
  u16* AO = xb;            // x dead after QKV projection

  detect_f32<<<32, 256, 0, stream>>>((const u16*)x, flag);
  prep_fused<<<14336, 256, 0, stream>>>(x, wq, wkv, xb, wqd, Wbuf, flag);
  gemm8qkv<<<dim3(24, 16), 512, 0, stream>>>(xb, wqd, Wbuf, Qb, KVb);
  mid_fused<<<24576, 256, 0, stream>>>(KVb, Wbuf, Qb);  // Wbuf := Vt
  flash_attn<<<dim3(32, 16), 512, 0, stream>>>(Qb, KVb, Wbuf, AO);
  convert_in8<<<2048, 256, 0, stream>>>(wo, Wbuf, 524288, flag);
  gemm_nt<<<dim3(16, 32), 256, 0, stream>>>(AO, Wbuf, d_out, 4096, 2048, 2048, flag, 1);
}

// Round 13
// 414.262 us; speedup vs baseline: 1.0116x; 1.0116x over previous
//
#include <hip/hip_runtime.h>
#include <stdint.h>

typedef unsigned short u16;
typedef __attribute__((ext_vector_type(8))) short short8;
typedef __attribute__((ext_vector_type(4))) float floatx4;

#define MFMA16(a, b, c) __builtin_amdgcn_mfma_f32_16x16x32_bf16(a, b, c, 0, 0, 0)

static __device__ __forceinline__ void gl_lds16(const void* g, void* l) {
  __builtin_amdgcn_global_load_lds(
      (const __attribute__((address_space(1))) uint32_t*)g,
      (__attribute__((address_space(3))) uint32_t*)l, 16, 0, 0);
}

static __device__ __forceinline__ float b2f(u16 u) {
  union { float f; unsigned u; } v;
  v.u = ((unsigned)u) << 16;
  return v.f;
}
static __device__ __forceinline__ u16 f2b(float f) {
  union { float f; unsigned u; } v;
  v.f = f;
  unsigned r = v.u + 0x7fffu + ((v.u >> 16) & 1u);  // RNE
  return (u16)(r >> 16);
}
// Cheap round-half-up bf16 (2 VALU ops). P-store only (values in [0,1]).
static __device__ __forceinline__ u16 f2b_rn(float f) {
  union { float f; unsigned u; } v;
  v.f = f;
  return (u16)((v.u + 0x8000u) >> 16);
}

// flag[0..31]: per-block large-exponent counts (plain stores from detect;
// idempotent across graph replays — no memset node needed).
static __device__ __forceinline__ int is_f32(const int* __restrict__ flag) {
  int s = 0;
#pragma unroll
  for (int i = 0; i < 32; ++i) s += flag[i];
  return s > 1000;
}

// DPP row-rotate reductions over 16-lane groups (VALU, no LDS traffic).
template <int CTRL>
static __device__ __forceinline__ float dppf(float x) {
  return __builtin_bit_cast(
      float, __builtin_amdgcn_update_dpp(0, __builtin_bit_cast(int, x), CTRL,
                                         0xF, 0xF, true));
}
static __device__ __forceinline__ float sum16(float x) {
  x += dppf<0x128>(x);
  x += dppf<0x124>(x);
  x += dppf<0x122>(x);
  x += dppf<0x121>(x);
  return x;
}
static __device__ __forceinline__ float max16(float x) {
  x = fmaxf(x, dppf<0x128>(x));
  x = fmaxf(x, dppf<0x124>(x));
  x = fmaxf(x, dppf<0x122>(x));
  x = fmaxf(x, dppf<0x121>(x));
  return x;
}

// ---------------------------------------------------------------------------
// Input-dtype detector (parallel, proven; per-block plain stores).
// ---------------------------------------------------------------------------
__global__ __launch_bounds__(256) void detect_f32(const u16* __restrict__ x,
                                                  int* __restrict__ flag) {
  __shared__ int cnt[256];
  int i = blockIdx.x * 256 + threadIdx.x;  // 8192 threads x 8 u16 = 64K u16
  short8 v = ((const short8*)x)[i];
  int c = 0;
#pragma unroll
  for (int j = 0; j < 8; ++j) {
    int e = (((unsigned short)v[j]) >> 7) & 0xFF;
    c += (e >= 140) ? 1 : 0;
  }
  cnt[threadIdx.x] = c;
  __syncthreads();
  for (int s = 128; s > 0; s >>= 1) {
    if (threadIdx.x < (unsigned)s) cnt[threadIdx.x] += cnt[threadIdx.x + s];
    __syncthreads();
  }
  if (threadIdx.x == 0) flag[blockIdx.x] = cnt[0];
}

static __device__ __forceinline__ void conv8_body(const void* __restrict__ src,
                                                  u16* __restrict__ dst, int i,
                                                  int f32) {
  short8 r;
  if (f32) {
    const float4* s = (const float4*)src;
    float4 a = s[2 * i], b = s[2 * i + 1];
    r[0] = (short)f2b(a.x); r[1] = (short)f2b(a.y);
    r[2] = (short)f2b(a.z); r[3] = (short)f2b(a.w);
    r[4] = (short)f2b(b.x); r[5] = (short)f2b(b.y);
    r[6] = (short)f2b(b.z); r[7] = (short)f2b(b.w);
  } else {
    r = ((const short8*)src)[i];
  }
  ((short8*)dst)[i] = r;
}

// Standalone convert (wo, post-flash).
__global__ __launch_bounds__(256) void convert_in8(const void* __restrict__ src,
                                                   u16* __restrict__ dst, int n8,
                                                   const int* __restrict__ flag) {
  int i = blockIdx.x * 256 + threadIdx.x;
  if (i >= n8) return;
  conv8_body(src, dst, i, is_f32(flag));
}

// ---------------------------------------------------------------------------
// prep_fused: convert x (bid<4096) + convert wq into d_out scratch
// (bid<6144; d_out dead until final O GEMM overwrites it — proven round 12) +
// transpose wkv -> Wbuf (bid<14336). Whole blocks per branch.
// ---------------------------------------------------------------------------
__global__ __launch_bounds__(256) void prep_fused(const void* __restrict__ x,
                                                  const void* __restrict__ wq,
                                                  const void* __restrict__ wkv,
                                                  u16* __restrict__ xb,
                                                  u16* __restrict__ wqd,
                                                  u16* __restrict__ wkvT,
                                                  const int* __restrict__ flag) {
  __shared__ u16 tile[32][33];
  int bid = blockIdx.x;
  int f = is_f32(flag);
  if (bid < 4096) {
    conv8_body(x, xb, bid * 256 + threadIdx.x, f);
  } else if (bid < 6144) {
    conv8_body(wq, wqd, (bid - 4096) * 256 + threadIdx.x, f);
  } else {
    int tb = bid - 6144;  // 0..8191: wkv [2048][4096] -> wkvT [4096][2048]
    int c0 = (tb & 127) * 32, r0 = (tb >> 7) * 32;
    int lx = threadIdx.x & 31, ly = threadIdx.x >> 5;
#pragma unroll
    for (int i = 0; i < 32; i += 8) {
      size_t idx = (size_t)(r0 + ly + i) * 4096 + c0 + lx;
      tile[ly + i][lx] = f ? f2b(((const float*)wkv)[idx]) : ((const u16*)wkv)[idx];
    }
    __syncthreads();
#pragma unroll
    for (int i = 0; i < 32; i += 8)
      wkvT[(size_t)(c0 + ly + i) * 2048 + r0 + lx] = tile[lx][ly + i];
  }
}

// ---------------------------------------------------------------------------
// mid_fused: transpose_v (bid<8192) + rope (bid>=8192). Q-scale now folds
// log2(e) as well: scale = log2(e)/sqrt(128) — softmax exps become bare
// v_exp_f32 (2^x) with no per-exp mul (round 13).
// ---------------------------------------------------------------------------
__global__ __launch_bounds__(256) void mid_fused(u16* __restrict__ KV,
                                                 u16* __restrict__ Vt,
                                                 u16* __restrict__ Q) {
  __shared__ u16 tile[32][33];
  int bid = blockIdx.x;
  if (bid < 8192) {
    int b = bid >> 12;
    int d0 = (bid & 63) * 32, s0 = ((bid >> 6) & 63) * 32;
    int lx = threadIdx.x & 31, ly = threadIdx.x >> 5;
    const u16* src = KV + ((size_t)(b * 2048 + s0)) * 4096 + 2048 + d0;
#pragma unroll
    for (int i = 0; i < 32; i += 8)
      tile[ly + i][lx] = src[(size_t)(ly + i) * 4096 + lx];
    __syncthreads();
    u16* dst = Vt + ((size_t)(b * 2048 + d0)) * 2048 + s0;
#pragma unroll
    for (int i = 0; i < 32; i += 8)
      dst[(size_t)(ly + i) * 2048 + lx] = tile[lx][ly + i];
  } else {
    const float scale = 0.12751744222f;  // log2(e)/sqrt(128)
    int idx = (bid - 8192) * 256 + threadIdx.x;
    int tok = idx >> 10;
    int rem = idx & 1023;
    int h = rem >> 6, i = rem & 63;
    int pos = tok & 2047;
    float f = __powf(10000.0f, -(float)(2 * i) * (1.0f / 128.0f));
    float ang = (float)pos * f;
    float s, c;
    sincosf(ang, &s, &c);

    size_t qb = (size_t)tok * 2048 + h * 128 + i;
    float q1 = b2f(Q[qb]), q2 = b2f(Q[qb + 64]);
    Q[qb] = f2b((q1 * c - q2 * s) * scale);
    Q[qb + 64] = f2b((q2 * c + q1 * s) * scale);

    size_t kb = (size_t)tok * 4096 + h * 128 + i;
    float k1 = b2f(KV[kb]), k2 = b2f(KV[kb + 64]);
    KV[kb] = f2b(k1 * c - k2 * s);
    KV[kb + 64] = f2b(k2 * c + k1 * s);
  }
}

// ---------------------------------------------------------------------------
// NT GEMM (m97 structure, proven) — Q and O projections (512-block grids).
// ---------------------------------------------------------------------------
__global__ __launch_bounds__(256) void gemm_nt(const u16* __restrict__ A,
                                               const u16* __restrict__ Bm,
                                               void* __restrict__ Cv,
                                               int M, int N, int K,
                                               const int* __restrict__ flag,
                                               int flag_mode) {
  __shared__ u16 Ash[128 * 64];
  __shared__ u16 Bsh[128 * 64];
  int tid = threadIdx.x, w = tid >> 6, lane = tid & 63;
  int quad = lane >> 4, l15 = lane & 15;
  int m0 = blockIdx.y * 128, n0 = blockIdx.x * 128;
  int wm = (w & 1) * 64, wn = (w >> 1) * 64;
  int f32out = flag_mode ? is_f32(flag) : 0;

  floatx4 acc[4][4];
#pragma unroll
  for (int i = 0; i < 4; ++i)
#pragma unroll
    for (int j = 0; j < 4; ++j) acc[i][j] = floatx4{0.f, 0.f, 0.f, 0.f};

  int srow = lane >> 3;
  int gch = (lane & 7) ^ srow;
  const u16* Ag = A + (size_t)(m0 + w * 32 + srow) * K + gch * 8;
  const u16* Bg = Bm + (size_t)(n0 + w * 32 + srow) * K + gch * 8;

  for (int k0 = 0; k0 < K; k0 += 64) {
    __syncthreads();
#pragma unroll
    for (int t = 0; t < 4; ++t) {
      gl_lds16(Ag + (size_t)t * 8 * K + k0, (void*)(Ash + (w * 32 + t * 8) * 64));
      gl_lds16(Bg + (size_t)t * 8 * K + k0, (void*)(Bsh + (w * 32 + t * 8) * 64));
    }
    __syncthreads();
#pragma unroll
    for (int kk = 0; kk < 2; ++kk) {
      int c = kk * 4 + quad;
      short8 af[4], bf[4];
#pragma unroll
      for (int i = 0; i < 4; ++i) {
        int m = wm + 16 * i + l15;
        af[i] = *(const short8*)(Ash + m * 64 + ((c ^ (m & 7)) << 3));
        int n = wn + 16 * i + l15;
        bf[i] = *(const short8*)(Bsh + n * 64 + ((c ^ (n & 7)) << 3));
      }
#pragma unroll
      for (int i = 0; i < 4; ++i)
#pragma unroll
        for (int j = 0; j < 4; ++j) acc[i][j] = MFMA16(af[i], bf[j], acc[i][j]);
    }
  }

#pragma unroll
  for (int i = 0; i < 4; ++i)
#pragma unroll
    for (int r = 0; r < 4; ++r) {
      int row = m0 + wm + 16 * i + quad * 4 + r;
      if (f32out) {
        float* cp = (float*)Cv + (size_t)row * N + n0 + wn + l15;
#pragma unroll
        for (int j = 0; j < 4; ++j) cp[16 * j] = acc[i][j][r];
      } else {
        u16* cp = (u16*)Cv + (size_t)row * N + n0 + wn + l15;
#pragma unroll
        for (int j = 0; j < 4; ++j) cp[16 * j] = f2b(acc[i][j][r]);
      }
    }
}

// ---------------------------------------------------------------------------
// 8-phase 256x256 NT GEMM (m201 template) — KV projection. Grid MUST be
// exactly 256 blocks (1 block/CU at 128K LDS; round 12's 384-block merge
// cost a full second half-idle round, +25us).
// ---------------------------------------------------------------------------
__global__ __launch_bounds__(512, 2) void gemm8(const u16* __restrict__ A,
                                                const u16* __restrict__ Bm,
                                                void* __restrict__ Cv,
                                                int M, int N, int K,
                                                const int* __restrict__ flag,
                                                int flag_mode) {
  __shared__ u16 Ash[2 * 256 * 64];
  __shared__ u16 Bsh[2 * 256 * 64];
  int tid = threadIdx.x, w = tid >> 6, lane = tid & 63;
  int quad = lane >> 4, l15 = lane & 15;
  int wr = w >> 2, wc = w & 3;
  int wm = wr * 128, wn = wc * 64;
  int m0 = blockIdx.y * 256, n0 = blockIdx.x * 256;
  int f32out = flag_mode ? is_f32(flag) : 0;
  const int NT = K >> 6;

  int srow8 = lane >> 3;
  int gch = (lane & 7) ^ srow8;
  const u16* Ag = A + (size_t)(m0 + w * 8 + srow8) * K + gch * 8;
  const u16* Bg = Bm + (size_t)(n0 + w * 8 + srow8) * K + gch * 8;
  int ldsrow = w * 8;  // wave-uniform LDS row base; lane*16B added by HW

  floatx4 acc[8][4];
#pragma unroll
  for (int i = 0; i < 8; ++i)
#pragma unroll
    for (int j = 0; j < 4; ++j) acc[i][j] = floatx4{0.f, 0.f, 0.f, 0.f};

  int ch0 = ((quad ^ (l15 & 7)) << 3);        // kk=0 chunk byte-> u16 offset
  int ch1 = (((4 + quad) ^ (l15 & 7)) << 3);  // kk=1

  auto stage = [&](int qi) {
    int tau = qi >> 2;
    int tc = tau < NT ? tau : NT - 1;  // clamp keeps vmcnt counts exact
    int hh = qi & 3;                   // 0:B0 1:B1 2:A0 3:A1
    int half = (hh & 1) * 128;
    int sbuf = (tau & 1) * (256 * 64);
    size_t kof = (size_t)tc * 64;
    if (hh < 2) {
      gl_lds16(Bg + (size_t)half * K + kof,
               (void*)(Bsh + sbuf + (half + ldsrow) * 64));
      gl_lds16(Bg + (size_t)(half + 64) * K + kof,
               (void*)(Bsh + sbuf + (half + 64 + ldsrow) * 64));
    } else {
      gl_lds16(Ag + (size_t)half * K + kof,
               (void*)(Ash + sbuf + (half + ldsrow) * 64));
      gl_lds16(Ag + (size_t)(half + 64) * K + kof,
               (void*)(Ash + sbuf + (half + 64 + ldsrow) * 64));
    }
  };

  // Prologue: tile0 fully + 3 half-tiles of tile1 -> 3 half-tiles in flight.
  stage(0); stage(1); stage(2); stage(3);
  __asm__ volatile("s_waitcnt vmcnt(4)" ::: "memory");
  stage(4); stage(5); stage(6);
  __asm__ volatile("s_waitcnt vmcnt(6)" ::: "memory");
  __builtin_amdgcn_s_barrier();

  for (int t = 0; t < NT; ++t) {
    u16* As = Ash + (t & 1) * (256 * 64);
    u16* Bs = Bsh + (t & 1) * (256 * 64);
    if (t) {
      __asm__ volatile("s_waitcnt vmcnt(6)" ::: "memory");
      __builtin_amdgcn_s_barrier();
    }
    int qb = 7 + 4 * t;
    short8 bf[8], af0[8], af1[8];

    // ---- P0: read af0-kk0 + bf-kk0 (8 reads); MFMA mh0 x kk0 (16) ----
#pragma unroll
    for (int j = 0; j < 4; ++j) {
      int n = wn + 16 * j + l15;
      bf[2 * j] = *(const short8*)(Bs + n * 64 + ch0);
    }
#pragma unroll
    for (int i = 0; i < 4; ++i) {
      int m = wm + 16 * i + l15;
      af0[2 * i] = *(const short8*)(As + m * 64 + ch0);
    }
    stage(qb);
    __builtin_amdgcn_s_barrier();
    __asm__ volatile("s_waitcnt lgkmcnt(0)" ::: "memory");
    __builtin_amdgcn_sched_barrier(0);
    __builtin_amdgcn_s_setprio(1);
#pragma unroll
    for (int i = 0; i < 4; ++i)
#pragma unroll
      for (int j = 0; j < 4; ++j)
        acc[i][j] = MFMA16(af0[2 * i], bf[2 * j], acc[i][j]);
    __builtin_amdgcn_s_setprio(0);
    __builtin_amdgcn_s_barrier();

    // ---- P1: read af0-kk1 + bf-kk1 (8 reads); MFMA mh0 x kk1 (16) ----
#pragma unroll
    for (int j = 0; j < 4; ++j) {
      int n = wn + 16 * j + l15;
      bf[2 * j + 1] = *(const short8*)(Bs + n * 64 + ch1);
    }
#pragma unroll
    for (int i = 0; i < 4; ++i) {
      int m = wm + 16 * i + l15;
      af0[2 * i + 1] = *(const short8*)(As + m * 64 + ch1);
    }
    stage(qb + 1);
    __builtin_amdgcn_s_barrier();
    __asm__ volatile("s_waitcnt lgkmcnt(0)" ::: "memory");
    __builtin_amdgcn_sched_barrier(0);
    __builtin_amdgcn_s_setprio(1);
#pragma unroll
    for (int i = 0; i < 4; ++i)
#pragma unroll
      for (int j = 0; j < 4; ++j)
        acc[i][j] = MFMA16(af0[2 * i + 1], bf[2 * j + 1], acc[i][j]);
    __builtin_amdgcn_s_setprio(0);
    __builtin_amdgcn_s_barrier();

    // ---- P2: read af1-kk0 (4 reads); MFMA mh1 x kk0 (16) ----
#pragma unroll
    for (int i = 0; i < 4; ++i) {
      int m = wm + 64 + 16 * i + l15;
      af1[2 * i] = *(const short8*)(As + m * 64 + ch0);
    }
    stage(qb + 2);
    __builtin_amdgcn_s_barrier();
    __asm__ volatile("s_waitcnt lgkmcnt(0)" ::: "memory");
    __builtin_amdgcn_sched_barrier(0);
    __builtin_amdgcn_s_setprio(1);
#pragma unroll
    for (int i = 0; i < 4; ++i)
#pragma unroll
      for (int j = 0; j < 4; ++j)
        acc[4 + i][j] = MFMA16(af1[2 * i], bf[2 * j], acc[4 + i][j]);
    __builtin_amdgcn_s_setprio(0);
    __builtin_amdgcn_s_barrier();

    // ---- P3: read af1-kk1 (4 reads); MFMA mh1 x kk1 (16) ----
#pragma unroll
    for (int i = 0; i < 4; ++i) {
      int m = wm + 64 + 16 * i + l15;
      af1[2 * i + 1] = *(const short8*)(As + m * 64 + ch1);
    }
    stage(qb + 3);
    __builtin_amdgcn_s_barrier();
    __asm__ volatile("s_waitcnt lgkmcnt(0)" ::: "memory");
    __builtin_amdgcn_sched_barrier(0);
    __builtin_amdgcn_s_setprio(1);
#pragma unroll
    for (int i = 0; i < 4; ++i)
#pragma unroll
      for (int j = 0; j < 4; ++j)
        acc[4 + i][j] = MFMA16(af1[2 * i + 1], bf[2 * j + 1], acc[4 + i][j]);
    __builtin_amdgcn_s_setprio(0);
    __builtin_amdgcn_s_barrier();
  }

  // Epilogue (same C/D mapping as proven gemm_nt).
#pragma unroll
  for (int i = 0; i < 8; ++i)
#pragma unroll
    for (int r = 0; r < 4; ++r) {
      int row = m0 + wm + 16 * i + quad * 4 + r;
      if (f32out) {
        float* cp = (float*)Cv + (size_t)row * N + n0 + wn + l15;
#pragma unroll
        for (int j = 0; j < 4; ++j) cp[16 * j] = acc[i][j][r];
      } else {
        u16* cp = (u16*)Cv + (size_t)row * N + n0 + wn + l15;
#pragma unroll
        for (int j = 0; j < 4; ++j) cp[16 * j] = f2b(acc[i][j][r]);
      }
    }
}

// ---------------------------------------------------------------------------
// Flash attention v11: v10 + exp2 folding — Q carries log2(e)/sqrt(dh), so
// all softmax exps are bare exp2f (v_exp_f32 computes 2^x natively; saves
// one v_mul per exp, ~36 VALU/tile). Values of P and alpha unchanged.
// ---------------------------------------------------------------------------
__global__ __launch_bounds__(512, 1) void flash_attn(const u16* __restrict__ Q,
                                                     const u16* __restrict__ KV,
                                                     const u16* __restrict__ Vt,
                                                     u16* __restrict__ O) {
  const int S = 2048, D = 2048, KVld = 4096;
  int bh = blockIdx.x;            // 0..31
  int qt = 15 - (int)blockIdx.y;  // heavy-first dispatch
  int b = bh >> 4, h = bh & 15;
  int tid = threadIdx.x, w = tid >> 6, lane = tid & 63;
  int quad = lane >> 4, l15 = lane & 15;

  const u16* Qb = Q + (size_t)(b * S) * D + h * 128;
  const u16* Kb = KV + (size_t)(b * S) * KVld + h * 128;
  const u16* Vtb = Vt + ((size_t)(b * 2048 + h * 128)) * S;

  __shared__ u16 Ksh[128 * 128];     // single buf [krow][d], 16 chunks/row
  __shared__ u16 Vsh[2][128 * 128];  // dbuf [d][k], 16 chunks/row
  __shared__ u16 Psh[8][16 * 128];   // per-wave P [16 q][128 k]

  // K tile [128 rows][128 d]: wave w rows w*16..w*16+16, 4 instrs.
  auto stage_k = [&](int kt) {
    int kb = kt * 128;
#pragma unroll
    for (int tt = 0; tt < 4; ++tt) {
      int r0 = w * 16 + tt * 4;
      int row = r0 + quad;
      int g = (l15 & 8) | ((l15 & 7) ^ (row & 7));
      gl_lds16(Kb + (size_t)(kb + row) * KVld + g * 8, (void*)(Ksh + r0 * 128));
    }
  };
  // V^T tile [128 d][128 k]: wave w d-rows w*16..w*16+16, 4 instrs.
  auto stage_v = [&](int kt, int buf) {
    int kb = kt * 128;
#pragma unroll
    for (int tt = 0; tt < 4; ++tt) {
      int d0 = w * 16 + tt * 4;
      int d = d0 + quad;
      int g = (l15 & 8) | ((l15 & 7) ^ (d & 7));
      gl_lds16(Vtb + (size_t)d * S + kb + g * 8, (void*)(Vsh[buf] + d0 * 128));
    }
  };

  int qw = qt * 128 + w * 16;  // this wave's 16 q-rows

  short8 qf[4];
  {
    const u16* qp = Qb + (size_t)(qw + l15) * D + quad * 8;
#pragma unroll
    for (int kk = 0; kk < 4; ++kk) qf[kk] = *(const short8*)(qp + kk * 32);
  }

  floatx4 o[8];
#pragma unroll
  for (int t = 0; t < 8; ++t) o[t] = floatx4{0.f, 0.f, 0.f, 0.f};
  float mrow[4], lrow[4];
#pragma unroll
  for (int r = 0; r < 4; ++r) { mrow[r] = -1e30f; lrow[r] = 0.f; }

  int nk = qt + 1;  // 128-wide k-tiles
  stage_k(0);
  stage_v(0, 0);
  __syncthreads();

  for (int kt = 0; kt < nk; ++kt) {
    int kb = kt * 128;
    int cur = kt & 1;

    // --- QK^T: 8 nf x 4 kk = 32 MFMA (reads Ksh) ---
    floatx4 sc[8];
#pragma unroll
    for (int nf = 0; nf < 8; ++nf) sc[nf] = floatx4{0.f, 0.f, 0.f, 0.f};
#pragma unroll
    for (int kk = 0; kk < 4; ++kk) {
      int c = kk * 4 + quad;
#pragma unroll
      for (int nf = 0; nf < 8; ++nf) {
        int n = nf * 16 + l15;
        int pc = (c & 8) | ((c & 7) ^ (n & 7));
        short8 kf = *(const short8*)(Ksh + n * 128 + pc * 8);
        sc[nf] = MFMA16(qf[kk], kf, sc[nf]);
      }
    }
    // #1: all waves' K reads complete
    __syncthreads();
    // prefetch next tile: K into the (now unread) single buffer, V into buf^1
    if (kt + 1 < nk) {
      stage_k(kt + 1);
      stage_v(kt + 1, cur ^ 1);
    }

    // --- online softmax (log2e/sqrt(dh) pre-folded into Q; exp2 domain) ---
    bool masked = (kb + 127 > qw);
    floatx4 alv;
#pragma unroll
    for (int r = 0; r < 4; ++r) {
      int qg = qw + quad * 4 + r;
      float p[8];
#pragma unroll
      for (int g = 0; g < 8; ++g) {
        float vg = sc[g][r];
        if (masked) vg = (kb + 16 * g + l15 <= qg) ? vg : -1e30f;
        p[g] = vg;
      }
      float mx = fmaxf(fmaxf(fmaxf(p[0], p[1]), fmaxf(p[2], p[3])),
                       fmaxf(fmaxf(p[4], p[5]), fmaxf(p[6], p[7])));
      mx = max16(mx);
      float mn = fmaxf(mrow[r], mx);
      float al = exp2f(mrow[r] - mn);
      mrow[r] = mn;
      float rs = 0.f;
#pragma unroll
      for (int g = 0; g < 8; ++g) {
        p[g] = exp2f(p[g] - mn);
        rs += p[g];
      }
      rs = sum16(rs);
      lrow[r] = lrow[r] * al + rs;
      alv[r] = al;
      int m_ = quad * 4 + r;
      int sw = (m_ & 3) ^ ((m_ >> 2) << 1);
      int cb = l15 >> 3, e = l15 & 7;
      u16* pr = Psh[w] + m_ * 128;
#pragma unroll
      for (int g = 0; g < 8; ++g)
        pr[(((2 * g + cb) ^ sw) << 3) + e] = f2b_rn(p[g]);
    }
    // defer-rescale: al==1.0 exactly when the running max didn't grow.
    if (__any((alv[0] != 1.f) || (alv[1] != 1.f) ||
              (alv[2] != 1.f) || (alv[3] != 1.f))) {
#pragma unroll
      for (int t = 0; t < 8; ++t) o[t] *= alv;
    }
    __asm__ volatile("s_waitcnt lgkmcnt(0)" ::: "memory");

    // --- PV: 8 d x 4 ksteps = 32 MFMA (reads Vsh[cur] + Psh[w]) ---
    int psw = (l15 & 3) ^ ((l15 >> 2) << 1);
#pragma unroll
    for (int ks = 0; ks < 4; ++ks) {
      int c = ks * 4 + quad;
      short8 pf = *(const short8*)(Psh[w] + l15 * 128 + ((c ^ psw) << 3));
#pragma unroll
      for (int t = 0; t < 8; ++t) {
        int d = t * 16 + l15;
        int pc = (c & 8) | ((c & 7) ^ (d & 7));
        short8 vf = *(const short8*)(Vsh[cur] + d * 128 + pc * 8);
        o[t] = MFMA16(pf, vf, o[t]);
      }
    }
    // #2: drains this wave's prefetch gl_lds + joins waves.
    __syncthreads();
  }

  // epilogue
#pragma unroll
  for (int r = 0; r < 4; ++r) {
    float inv = 1.0f / lrow[r];
    int qg = qw + quad * 4 + r;
    u16* op = O + (size_t)(b * S + qg) * D + h * 128;
#pragma unroll
    for (int t = 0; t < 8; ++t) op[t * 16 + l15] = f2b(o[t][r] * inv);
  }
}

// ---------------------------------------------------------------------------
// Launch (round 13: 8 nodes — round-11 split restored; gemm8qkv's 384-block
// grid cost a half-idle second round). ws (u16 after 64-elem flag pad):
//   xb 8.4M | Wbuf 8.4M (wkvT -> Vt -> wo) | Qb 8.4M | KVb 16.8M. ~84 MB.
//   wq staged in d_out (dead scratch; final O GEMM fully overwrites).
//   AO aliases xb.
// ---------------------------------------------------------------------------
extern "C" void kernel_launch(void* const* d_in, const int* in_sizes, int n_in,
                              void* d_out, int out_size, void* d_ws, size_t ws_size,
                              hipStream_t stream) {
  const void* x = d_in[0];
  const void* wq = d_in[1];
  const void* wkv = d_in[2];
  const void* wo = d_in[3];

  int* flag = (int*)d_ws;  // 32 ints (128 B = the 64-u16 pad)
  u16* xb = (u16*)d_ws + 64;
  u16* Wbuf = xb + (size_t)8388608;
  u16* Qb = Wbuf + (size_t)8388608;
  u16* KVb = Qb + (size_t)8388608;
  u16* wqd = (u16*)d_out;  // wq scratch in d_out (dead until final GEMM)
  u16* AO = xb;            // x dead after QKV projection

  detect_f32<<<32, 256, 0, stream>>>((const u16*)x, flag);
  prep_fused<<<14336, 256, 0, stream>>>(x, wq, wkv, xb, wqd, Wbuf, flag);
  gemm_nt<<<dim3(16, 32), 256, 0, stream>>>(xb, wqd, Qb, 4096, 2048, 2048, flag, 0);
  gemm8<<<dim3(16, 16), 512, 0, stream>>>(xb, Wbuf, KVb, 4096, 4096, 2048, flag, 0);
  mid_fused<<<24576, 256, 0, stream>>>(KVb, Wbuf, Qb);  // Wbuf := Vt
  flash_attn<<<dim3(32, 16), 512, 0, stream>>>(Qb, KVb, Wbuf, AO);
  convert_in8<<<2048, 256, 0, stream>>>(wo, Wbuf, 524288, flag);
  gemm_nt<<<dim3(16, 32), 256, 0, stream>>>(AO, Wbuf, d_out, 4096, 2048, 2048, flag, 1);
}